// Round 1
// 245.975 us; speedup vs baseline: 1.1885x; 1.1885x over previous
//
#include <hip/hip_runtime.h>
#include <hip/hip_bf16.h>

#define B_  4
#define D_  1024
#define L_  2048
#define H_  8
#define HD_ 128

typedef __attribute__((ext_vector_type(8))) short bf16x8;
typedef __attribute__((ext_vector_type(4))) float f32x4;

static __device__ __forceinline__ ushort f2bf(float f) {
    // round-to-nearest-even fp32 -> bf16 (finite inputs only)
    unsigned u = __float_as_uint(f);
    unsigned r = (u + 0x7fffu + ((u >> 16) & 1u)) >> 16;
    return (ushort)r;
}

// async 16B global->LDS DMA (dest = wave-uniform LDS base + lane*16)
static __device__ __forceinline__ void dma16(const ushort* g, ushort* l) {
    __builtin_amdgcn_global_load_lds(
        (const __attribute__((address_space(1))) void*)g,
        (__attribute__((address_space(3))) void*)l, 16, 0, 0);
}

// ---------------- signal kernel: zero output (signature absmax = 4.589844e-01) ----
__global__ void k_zero_out(float* __restrict__ out, int n) {
    int i = blockIdx.x * 256 + threadIdx.x;
    if (i < n) out[i] = 0.f;
}

// ---------------- Kernel A1: W1||Wq -> bf16 Wb [3072][1024] ----------------
__global__ void k_convert_w(const float* __restrict__ W1, const float* __restrict__ Wq,
                            ushort* __restrict__ Wb) {
    int i = blockIdx.x * 256 + threadIdx.x;     // float4 index, exact grid
    const int n1 = 2 * D_ * D_ / 4;             // 524288 float4s in W1
    float4 v = (i < n1) ? ((const float4*)W1)[i] : ((const float4*)Wq)[i - n1];
    ushort4 o;
    o.x = f2bf(v.x); o.y = f2bf(v.y); o.z = f2bf(v.z); o.w = f2bf(v.w);
    ((ushort4*)Wb)[i] = o;
}

// ---------------- Kernel A2: query[b][d][l] fp32 -> Xt[b][l][d] bf16 ----------------
__global__ void k_transpose(const float* __restrict__ q, ushort* __restrict__ Xt) {
    __shared__ float tile[32][33];
    int b = blockIdx.z, d0 = blockIdx.y * 32, l0 = blockIdx.x * 32;
    int tx = threadIdx.x, ty = threadIdx.y;
    const float* src = q + (size_t)b * D_ * L_;
    for (int i = 0; i < 4; i++)
        tile[ty + 8 * i][tx] = src[(size_t)(d0 + ty + 8 * i) * L_ + l0 + tx];
    __syncthreads();
    ushort* dst = Xt + (size_t)b * L_ * D_;
    for (int i = 0; i < 4; i++)
        dst[(size_t)(l0 + ty + 8 * i) * D_ + d0 + tx] = f2bf(tile[tx][ty + 8 * i]);
}

// ---------------- Kernel A3: mask scan -> compacted key index list + count --------
// One wave per batch. cidx[b][j] = original l of j-th unmasked key; pad with 0.
__global__ void k_scan(const int* __restrict__ mask, int* __restrict__ cidx,
                       int* __restrict__ cnt) {
    int b = blockIdx.x;
    int lane = threadIdx.x;                      // block = 64 (one wave)
    const int* mb = mask + b * L_;
    int base = 0;
    for (int c = 0; c < L_; c += 64) {
        int m = mb[c + lane];
        unsigned long long bal = __ballot(m != 0);
        int pre = __popcll(bal & ((1ull << lane) - 1ull));
        if (m) cidx[b * L_ + base + pre] = c + lane;
        base += __popcll(bal);
    }
    for (int j = base + lane; j < L_; j += 64) cidx[b * L_ + j] = 0;  // finite pad rows
    if (lane == 0) cnt[b] = base;
}

// ---------------- Kernel B: projection GEMM (MFMA) ------------------------------
// K/V output types read Xt rows through cidx (compacted key space) and skip
// l-tiles beyond ceil(count/128). Q type unchanged (all l needed).
__launch_bounds__(256)
__global__ void k_proj(const ushort* __restrict__ Wb, const ushort* __restrict__ Xt,
                       const int* __restrict__ cidx, const int* __restrict__ cnt,
                       ushort* __restrict__ Qb, ushort* __restrict__ Kb,
                       ushort* __restrict__ Vt) {
    __shared__ alignas(16) ushort As[128][72];   // [o][k], +8 pad
    __shared__ alignas(16) ushort Bs[128][72];   // [l][k]
    const int b  = blockIdx.z;
    const int o0 = blockIdx.y * 128;
    const int l0 = blockIdx.x * 128;
    const int type = o0 >> 10;                   // 0=K 1=V 2=Q (tile never crosses)
    if (type < 2) {                              // compacted key space: skip dead tiles
        int tiles = (cnt[b] + 127) >> 7;
        if (blockIdx.x >= tiles) return;         // uniform; before any barrier
    }
    const int t = threadIdx.x;
    const int wave = t >> 6, lane = t & 63, quad = lane >> 4, li = lane & 15;
    const int wm = wave >> 1, wn = wave & 1;
    const ushort* Xb = Xt + (size_t)b * L_ * D_;
    f32x4 acc[4][4] = {};
    const int row = t >> 3;     // 0..31
    const int chunk = t & 7;    // 0..7 (8 bf16 each)

    // per-thread row base pointers (gather through cidx for K/V types)
    const ushort* arow[4];
    const ushort* brow[4];
    for (int i = 0; i < 4; i++) {
        int r = row + 32 * i;
        arow[i] = Wb + (size_t)(o0 + r) * D_;
        int l = l0 + r;
        int gl = (type < 2) ? cidx[b * L_ + l] : l;
        brow[i] = Xb + (size_t)gl * D_;
    }

    for (int k0 = 0; k0 < D_; k0 += 64) {
        for (int i = 0; i < 4; i++) {
            int r = row + 32 * i;
            *(float4*)&As[r][chunk * 8] = *(const float4*)&arow[i][k0 + chunk * 8];
            *(float4*)&Bs[r][chunk * 8] = *(const float4*)&brow[i][k0 + chunk * 8];
        }
        __syncthreads();
        for (int ks = 0; ks < 64; ks += 32) {
            bf16x8 af[4], bfr[4];
            for (int mf = 0; mf < 4; mf++) af[mf]  = *(const bf16x8*)&As[wm * 64 + mf * 16 + li][ks + quad * 8];
            for (int nf = 0; nf < 4; nf++) bfr[nf] = *(const bf16x8*)&Bs[wn * 64 + nf * 16 + li][ks + quad * 8];
            for (int mf = 0; mf < 4; mf++)
                for (int nf = 0; nf < 4; nf++)
                    acc[mf][nf] = __builtin_amdgcn_mfma_f32_16x16x32_bf16(af[mf], bfr[nf], acc[mf][nf], 0, 0, 0);
        }
        __syncthreads();
    }

    const float qscale = 0.08838834764831845f;  // HD^-0.5
    for (int mf = 0; mf < 4; mf++) {
        int o = o0 + wm * 64 + mf * 16 + quad * 4;  // v[r] is channel o+r
        int c = o & 1023;
        int h = c >> 7, hd = c & 127;
        for (int nf = 0; nf < 4; nf++) {
            int l = l0 + wn * 64 + nf * 16 + li;    // compacted j for K/V
            f32x4 v = acc[mf][nf];
            if (type == 0) {
                ushort4 s4 = { f2bf(v[0]), f2bf(v[1]), f2bf(v[2]), f2bf(v[3]) };
                *(ushort4*)&Kb[(((size_t)(b * H_ + h)) * L_ + l) * HD_ + hd] = s4;
            } else if (type == 1) {
                size_t base = (size_t)(b * H_ + h) * HD_;
                Vt[(base + hd + 0) * L_ + l] = f2bf(v[0]);
                Vt[(base + hd + 1) * L_ + l] = f2bf(v[1]);
                Vt[(base + hd + 2) * L_ + l] = f2bf(v[2]);
                Vt[(base + hd + 3) * L_ + l] = f2bf(v[3]);
            } else {
                ushort4 s4 = { f2bf(v[0] * qscale), f2bf(v[1] * qscale),
                               f2bf(v[2] * qscale), f2bf(v[3] * qscale) };
                *(ushort4*)&Qb[(((size_t)(b * H_ + h)) * L_ + l) * HD_ + hd] = s4;
            }
        }
    }
}

// ---------------- Kernel C: flash attention over COMPACTED keys ------------------
// block = (b, h, 64 q); 4 waves x 16 q; key blocks of 32; one barrier/iter.
// Only ~count[b] (~L/2) keys exist; no per-tile mask work (tail tile clamps).
__launch_bounds__(256, 4)
__global__ void k_attn(const ushort* __restrict__ Qb, const ushort* __restrict__ Kb,
                       const ushort* __restrict__ Vt, const int* __restrict__ mask,
                       float* __restrict__ out) {
    __shared__ alignas(16) ushort Ks[2][32][128];   // 16 KB [buf][key][hd-chunk swizzled]
    __shared__ alignas(16) ushort Vs[2][128][32];   // 16 KB [buf][hd][key-chunk swizzled]
    __shared__ alignas(16) ushort Pl[4][16][40];    //  5 KB per-wave P scratch [q][key+pad]
    const int blk = blockIdx.x;
    const int h = blk & 7, qt = (blk >> 3) & 31, b = blk >> 8;
    const int t = threadIdx.x;
    const int w = t >> 6, lane = t & 63, quad = lane >> 4, li = lane & 15;
    const int q0 = qt * 64 + w * 16;
    const ushort* Qh = Qb + (size_t)(b * H_ + h) * L_ * HD_;
    const ushort* Kh = Kb + (size_t)(b * H_ + h) * L_ * HD_;
    const ushort* Vh = Vt + (size_t)(b * H_ + h) * HD_ * L_;
    const int* mb = mask + b * L_;

    // block-uniform unmasked-key count (recomputed from mask: no d_out dependency)
    int cm = 0;
    for (int c = lane; c < L_; c += 64) cm += mb[c];
    cm += __shfl_xor(cm, 32, 64);
    cm += __shfl_xor(cm, 16, 64);
    cm += __shfl_xor(cm, 8, 64);
    cm += __shfl_xor(cm, 4, 64);
    cm += __shfl_xor(cm, 2, 64);
    cm += __shfl_xor(cm, 1, 64);
    const int cnt = cm;
    int cnt_pad = (cnt + 31) & ~31;
    if (cnt_pad < 32) cnt_pad = 32;              // NaN guard (unreachable for real input)

    // DMA source pointers (lane-dependent; per-tile offset added at issue).
    // K slot (key,p) holds global hd-chunk p ^ (key&15); lane -> key=seg*4+(l>>4), p=l&15.
    // V slot (hd,p)  holds global key-chunk p ^ (hd&3);  lane -> hd=seg*16+(l>>2), p=l&3.
    const ushort* kgp[2]; const ushort* vgp[2];
    for (int i = 0; i < 2; i++) {
        int seg = w * 2 + i;                       // 0..7
        int key = seg * 4 + (lane >> 4);           // 0..31
        int ck  = (lane & 15) ^ (key & 15);
        kgp[i] = Kh + (size_t)key * HD_ + ck * 8;
        int hd  = seg * 16 + (lane >> 2);          // 0..127
        int cv  = (lane & 3) ^ (hd & 3);
        vgp[i] = Vh + (size_t)hd * L_ + cv * 8;
    }

    // prologue: DMA tile 0 into buf 0
    for (int i = 0; i < 2; i++) dma16(kgp[i], &Ks[0][0][0] + (w * 2 + i) * 512);
    for (int i = 0; i < 2; i++) dma16(vgp[i], &Vs[0][0][0] + (w * 2 + i) * 512);

    // Q as B-fragments (global, linear): qf[kf], n = q = li
    bf16x8 qf[4];
    for (int kf = 0; kf < 4; kf++)
        qf[kf] = *(const bf16x8*)&Qh[(size_t)(q0 + li) * HD_ + kf * 32 + quad * 8];

    float mrun = -1e30f, lrun = 0.f;
    f32x4 acc[8] = {};   // PV C-layout: row q = quad*4+r, col hd = li + 16*nf2

    int buf = 0;
    for (int n0 = 0; n0 < cnt_pad; n0 += 32, buf ^= 1) {
        __syncthreads();   // buf's DMA drained+visible; all waves past prior buf reads

        if (n0 + 32 < cnt_pad) {  // uniform: issue next tile's DMA into other buffer
            int nb = buf ^ 1;
            for (int i = 0; i < 2; i++)
                dma16(kgp[i] + (size_t)(n0 + 32) * HD_, &Ks[nb][0][0] + (w * 2 + i) * 512);
            for (int i = 0; i < 2; i++)
                dma16(vgp[i] + (n0 + 32), &Vs[nb][0][0] + (w * 2 + i) * 512);
        }

        // S^T = K(A) x Q^T(B): s[mt][r]: key = mt*16+quad*4+r, q = li
        f32x4 s[2] = {};
        for (int kf = 0; kf < 4; kf++) {
            bf16x8 kfr[2];
            for (int mt = 0; mt < 2; mt++)
                kfr[mt] = *(const bf16x8*)&Ks[buf][mt * 16 + li][((kf * 4 + quad) ^ li) * 8];
            for (int mt = 0; mt < 2; mt++)
                s[mt] = __builtin_amdgcn_mfma_f32_16x16x32_bf16(kfr[mt], qf[kf], s[mt], 0, 0, 0);
        }

        if (n0 + 32 > cnt) {  // tail tile only (uniform branch): clamp pad keys
            for (int mt = 0; mt < 2; mt++)
                for (int r = 0; r < 4; r++)
                    if (n0 + mt * 16 + quad * 4 + r >= cnt) s[mt][r] = -1e30f;
        }

        // softmax over this 32-key tile (q = li)
        float a0 = fmaxf(fmaxf(s[0][0], s[0][1]), fmaxf(s[0][2], s[0][3]));
        float a1 = fmaxf(fmaxf(s[1][0], s[1][1]), fmaxf(s[1][2], s[1][3]));
        float nm = fmaxf(a0, a1);
        nm = fmaxf(nm, __shfl_xor(nm, 16, 64));
        nm = fmaxf(nm, __shfl_xor(nm, 32, 64));
        float mnew = fmaxf(mrun, nm);
        float alpha = __expf(mrun - mnew);
        mrun = mnew;
        float rs = 0.f;
        for (int mt = 0; mt < 2; mt++)
            for (int r = 0; r < 4; r++) {
                float p = __expf(s[mt][r] - mnew);
                s[mt][r] = p;
                rs += p;
            }
        rs += __shfl_xor(rs, 16, 64);
        rs += __shfl_xor(rs, 32, 64);
        lrun = lrun * alpha + rs;

        // rescale acc only when the running max actually moved (common case: skip)
        if (__any(alpha != 1.0f)) {
            int sb = (lane & 48) | (quad * 4);     // lane with li = quad*4 (+r)
            float ar0 = __shfl(alpha, sb + 0, 64);
            float ar1 = __shfl(alpha, sb + 1, 64);
            float ar2 = __shfl(alpha, sb + 2, 64);
            float ar3 = __shfl(alpha, sb + 3, 64);
            for (int nf2 = 0; nf2 < 8; nf2++) {
                acc[nf2][0] *= ar0;
                acc[nf2][1] *= ar1;
                acc[nf2][2] *= ar2;
                acc[nf2][3] *= ar3;
            }
        }

        // P write: Pl[w][q=li][key = mt*16+quad*4+r]
        for (int mt = 0; mt < 2; mt++) {
            ushort4 pk = { f2bf(s[mt][0]), f2bf(s[mt][1]),
                           f2bf(s[mt][2]), f2bf(s[mt][3]) };
            *(ushort4*)&Pl[w][li][mt * 16 + quad * 4] = pk;
        }

        // PV: A = P (per-wave LDS, m=q=li, k=key), B = V from staged LDS
        bf16x8 pa = *(const bf16x8*)&Pl[w][li][quad * 8];
        for (int nf2 = 0; nf2 < 8; nf2++) {
            bf16x8 vb = *(const bf16x8*)&Vs[buf][nf2 * 16 + li][(quad ^ (li & 3)) * 8];
            acc[nf2] = __builtin_amdgcn_mfma_f32_16x16x32_bf16(pa, vb, acc[nf2], 0, 0, 0);
        }
    }

    // epilogue: redistribute 1/l to row-space, float4 stores (4 consecutive l)
    float inv = 1.0f / lrun;
    int sb = (lane & 48) | (quad * 4);
    float i0 = __shfl(inv, sb + 0, 64);
    float i1 = __shfl(inv, sb + 1, 64);
    float i2 = __shfl(inv, sb + 2, 64);
    float i3 = __shfl(inv, sb + 3, 64);
    int l = q0 + quad * 4;
    for (int nf2 = 0; nf2 < 8; nf2++) {
        int d = h * HD_ + nf2 * 16 + li;
        float4 o4 = { acc[nf2][0] * i0, acc[nf2][1] * i1,
                      acc[nf2][2] * i2, acc[nf2][3] * i3 };
        *(float4*)&out[((size_t)(b * D_ + d)) * L_ + l] = o4;
    }
}

extern "C" void kernel_launch(void* const* d_in, const int* in_sizes, int n_in,
                              void* d_out, int out_size, void* d_ws, size_t ws_size,
                              hipStream_t stream) {
    // Bind inputs by element count (all distinct).
    const float* query = nullptr;  // 4*1024*2048 = 8388608
    const int*   mask  = nullptr;  // 4*2048     = 8192
    const float* W1    = nullptr;  // 2048*1024  = 2097152
    const float* Wq    = nullptr;  // 1024*1024  = 1048576
    for (int i = 0; i < n_in; i++) {
        switch (in_sizes[i]) {
            case 8388608: query = (const float*)d_in[i]; break;
            case 8192:    mask  = (const int*)d_in[i];   break;
            case 2097152: W1    = (const float*)d_in[i]; break;
            case 1048576: Wq    = (const float*)d_in[i]; break;
        }
    }
    float* out = (float*)d_out;  // [4,1024,2048] fp32 (reference output dtype)

    if (ws_size < 50331648u || !query || !mask || !W1 || !Wq) {
        hipLaunchKernelGGL(k_zero_out, dim3((out_size + 255) / 256), dim3(256), 0, stream,
                           out, out_size);
        return;
    }

    // d_out (32 MB fp32) is dead until k_attn -> use its head as projection scratch.
    // cidx/cnt also live here: written by k_scan, read ONLY by k_proj (pre-attn).
    ushort* Wb = (ushort*)d_out;                       // [3072][1024]      6291456 B
    ushort* Xt = (ushort*)((char*)d_out + 6291456);    // [4][2048][1024]  16777216 B
    int* cidx  = (int*)((char*)d_out + 23068672);      // [4][2048]           32768 B
    int* cnt   = (int*)((char*)d_out + 23101440);      // [4]                    16 B
    char* ws = (char*)d_ws;                            // Qb|Kb|Vt = 48 MB <= gate
    ushort* Qb = (ushort*)(ws + 0);
    ushort* Kb = (ushort*)(ws + 16777216);
    ushort* Vt = (ushort*)(ws + 33554432);

    hipLaunchKernelGGL(k_convert_w, dim3(3072), dim3(256), 0, stream, W1, Wq, Wb);
    hipLaunchKernelGGL(k_transpose, dim3(64, 32, 4), dim3(32, 8), 0, stream, query, Xt);
    hipLaunchKernelGGL(k_scan, dim3(4), dim3(64), 0, stream, mask, cidx, cnt);
    hipLaunchKernelGGL(k_proj, dim3(16, 24, 4), dim3(256), 0, stream, Wb, Xt, cidx, cnt, Qb, Kb, Vt);
    hipLaunchKernelGGL(k_attn, dim3(1024), dim3(256), 0, stream, Qb, Kb, Vt, mask, out);
}

// Round 2
// 241.792 us; speedup vs baseline: 1.2090x; 1.0173x over previous
//
#include <hip/hip_runtime.h>
#include <hip/hip_bf16.h>

#define B_  4
#define D_  1024
#define L_  2048
#define H_  8
#define HD_ 128

typedef __attribute__((ext_vector_type(8))) short bf16x8;
typedef __attribute__((ext_vector_type(4))) float f32x4;

static __device__ __forceinline__ ushort f2bf(float f) {
    // round-to-nearest-even fp32 -> bf16 (finite inputs only)
    unsigned u = __float_as_uint(f);
    unsigned r = (u + 0x7fffu + ((u >> 16) & 1u)) >> 16;
    return (ushort)r;
}

// async 16B global->LDS DMA (dest = wave-uniform LDS base + lane*16)
static __device__ __forceinline__ void dma16(const ushort* g, ushort* l) {
    __builtin_amdgcn_global_load_lds(
        (const __attribute__((address_space(1))) void*)g,
        (__attribute__((address_space(3))) void*)l, 16, 0, 0);
}

// ---------------- signal kernel: zero output (signature absmax = 4.589844e-01) ----
__global__ void k_zero_out(float* __restrict__ out, int n) {
    int i = blockIdx.x * 256 + threadIdx.x;
    if (i < n) out[i] = 0.f;
}

// ---------------- Kernel A1: W1||Wq -> bf16 Wb [3072][1024] ----------------
__global__ void k_convert_w(const float* __restrict__ W1, const float* __restrict__ Wq,
                            ushort* __restrict__ Wb) {
    int i = blockIdx.x * 256 + threadIdx.x;     // float4 index, exact grid
    const int n1 = 2 * D_ * D_ / 4;             // 524288 float4s in W1
    float4 v = (i < n1) ? ((const float4*)W1)[i] : ((const float4*)Wq)[i - n1];
    ushort4 o;
    o.x = f2bf(v.x); o.y = f2bf(v.y); o.z = f2bf(v.z); o.w = f2bf(v.w);
    ((ushort4*)Wb)[i] = o;
}

// ---------------- Kernel A2: query[b][d][l] fp32 -> Xt[b][l][d] bf16 ----------------
__global__ void k_transpose(const float* __restrict__ q, ushort* __restrict__ Xt) {
    __shared__ float tile[32][33];
    int b = blockIdx.z, d0 = blockIdx.y * 32, l0 = blockIdx.x * 32;
    int tx = threadIdx.x, ty = threadIdx.y;
    const float* src = q + (size_t)b * D_ * L_;
    for (int i = 0; i < 4; i++)
        tile[ty + 8 * i][tx] = src[(size_t)(d0 + ty + 8 * i) * L_ + l0 + tx];
    __syncthreads();
    ushort* dst = Xt + (size_t)b * L_ * D_;
    for (int i = 0; i < 4; i++)
        dst[(size_t)(l0 + ty + 8 * i) * D_ + d0 + tx] = f2bf(tile[tx][ty + 8 * i]);
}

// ---------------- Kernel A3: mask scan -> compacted key index list + count --------
// One wave per batch. cidx[b][j] = original l of j-th unmasked key; pad with 0.
__global__ void k_scan(const int* __restrict__ mask, int* __restrict__ cidx,
                       int* __restrict__ cnt) {
    int b = blockIdx.x;
    int lane = threadIdx.x;                      // block = 64 (one wave)
    const int* mb = mask + b * L_;
    int base = 0;
    for (int c = 0; c < L_; c += 64) {
        int m = mb[c + lane];
        unsigned long long bal = __ballot(m != 0);
        int pre = __popcll(bal & ((1ull << lane) - 1ull));
        if (m) cidx[b * L_ + base + pre] = c + lane;
        base += __popcll(bal);
    }
    for (int j = base + lane; j < L_; j += 64) cidx[b * L_ + j] = 0;  // finite pad rows
    if (lane == 0) cnt[b] = base;
}

// ---------------- Kernel B: projection GEMM (MFMA, async-DMA staging) -----------
// m97 structure: global_load_lds dwordx4 into LINEAR LDS [128][64]; XOR chunk
// swizzle applied on the per-lane GLOBAL source (dest must stay linear) and on
// the ds_read_b128 fragment reads. K/V types gather Xt rows through cidx
// (per-lane DMA source) and skip l-tiles beyond ceil(count/128).
__launch_bounds__(256)
__global__ void k_proj(const ushort* __restrict__ Wb, const ushort* __restrict__ Xt,
                       const int* __restrict__ cidx, const int* __restrict__ cnt,
                       ushort* __restrict__ Qb, ushort* __restrict__ Kb,
                       ushort* __restrict__ Vt) {
    __shared__ alignas(16) ushort As[128 * 64];   // 16 KB linear, swizzled content
    __shared__ alignas(16) ushort Bs[128 * 64];   // 16 KB linear, swizzled content
    const int b  = blockIdx.z;
    const int o0 = blockIdx.y * 128;
    const int l0 = blockIdx.x * 128;
    const int type = o0 >> 10;                   // 0=K 1=V 2=Q (tile never crosses)
    if (type < 2) {                              // compacted key space: skip dead tiles
        int tiles = (cnt[b] + 127) >> 7;
        if (blockIdx.x >= tiles) return;         // uniform; before any barrier
    }
    const int t = threadIdx.x;
    const int wave = t >> 6, lane = t & 63, quad = lane >> 4, li = lane & 15;
    const int wm = wave >> 1, wn = wave & 1;
    const ushort* Xb = Xt + (size_t)b * L_ * D_;

    // staging geometry: slot s = i*256 + t  ->  row = i*32 + (t>>3), phys chunk p = t&7
    // swizzle: slot (row,p) holds global 16B chunk g = p ^ (row&7);  row&7 == (t>>3)&7
    const int srow = t >> 3;                     // 0..31
    const int g = (t & 7) ^ (srow & 7);          // same for all 4 issues (32 | 8)
    const ushort* aSrc[4];
    const ushort* bSrc[4];
    for (int i = 0; i < 4; i++) {
        int r = i * 32 + srow;
        aSrc[i] = Wb + (size_t)(o0 + r) * D_ + g * 8;
        int l = l0 + r;
        int gl = (type < 2) ? cidx[b * L_ + l] : l;    // gather (per-lane DMA source)
        bSrc[i] = Xb + (size_t)gl * D_ + g * 8;
    }

    f32x4 acc[4][4] = {};

    for (int k0 = 0; k0 < D_; k0 += 64) {
        for (int i = 0; i < 4; i++)
            dma16(aSrc[i] + k0, &As[(i * 256 + wave * 64) * 8]);
        for (int i = 0; i < 4; i++)
            dma16(bSrc[i] + k0, &Bs[(i * 256 + wave * 64) * 8]);
        __syncthreads();   // compiler emits vmcnt(0) drain before barrier
        for (int ks = 0; ks < 64; ks += 32) {
            const int kc = ks >> 3;              // logical chunk base: 0 or 4
            bf16x8 af[4], bfr[4];
            // row&7 == li&7 for all fragment rows (wm*64, mf*16 are mult of 8)
            for (int mf = 0; mf < 4; mf++) {
                int row = wm * 64 + mf * 16 + li;
                af[mf] = *(const bf16x8*)&As[row * 64 + (((kc + quad) ^ (li & 7)) * 8)];
            }
            for (int nf = 0; nf < 4; nf++) {
                int row = wn * 64 + nf * 16 + li;
                bfr[nf] = *(const bf16x8*)&Bs[row * 64 + (((kc + quad) ^ (li & 7)) * 8)];
            }
            for (int mf = 0; mf < 4; mf++)
                for (int nf = 0; nf < 4; nf++)
                    acc[mf][nf] = __builtin_amdgcn_mfma_f32_16x16x32_bf16(af[mf], bfr[nf], acc[mf][nf], 0, 0, 0);
        }
        __syncthreads();   // all fragment reads done before next tile's DMA lands
    }

    const float qscale = 0.08838834764831845f;  // HD^-0.5
    for (int mf = 0; mf < 4; mf++) {
        int o = o0 + wm * 64 + mf * 16 + quad * 4;  // v[r] is channel o+r
        int c = o & 1023;
        int h = c >> 7, hd = c & 127;
        for (int nf = 0; nf < 4; nf++) {
            int l = l0 + wn * 64 + nf * 16 + li;    // compacted j for K/V
            f32x4 v = acc[mf][nf];
            if (type == 0) {
                ushort4 s4 = { f2bf(v[0]), f2bf(v[1]), f2bf(v[2]), f2bf(v[3]) };
                *(ushort4*)&Kb[(((size_t)(b * H_ + h)) * L_ + l) * HD_ + hd] = s4;
            } else if (type == 1) {
                size_t base = (size_t)(b * H_ + h) * HD_;
                Vt[(base + hd + 0) * L_ + l] = f2bf(v[0]);
                Vt[(base + hd + 1) * L_ + l] = f2bf(v[1]);
                Vt[(base + hd + 2) * L_ + l] = f2bf(v[2]);
                Vt[(base + hd + 3) * L_ + l] = f2bf(v[3]);
            } else {
                ushort4 s4 = { f2bf(v[0] * qscale), f2bf(v[1] * qscale),
                               f2bf(v[2] * qscale), f2bf(v[3] * qscale) };
                *(ushort4*)&Qb[(((size_t)(b * H_ + h)) * L_ + l) * HD_ + hd] = s4;
            }
        }
    }
}

// ---------------- Kernel C: flash attention over COMPACTED keys ------------------
// block = (b, h, 64 q); 4 waves x 16 q; key blocks of 32; one barrier/iter.
// Only ~count[b] (~L/2) keys exist; no per-tile mask work (tail tile clamps).
__launch_bounds__(256, 4)
__global__ void k_attn(const ushort* __restrict__ Qb, const ushort* __restrict__ Kb,
                       const ushort* __restrict__ Vt, const int* __restrict__ mask,
                       float* __restrict__ out) {
    __shared__ alignas(16) ushort Ks[2][32][128];   // 16 KB [buf][key][hd-chunk swizzled]
    __shared__ alignas(16) ushort Vs[2][128][32];   // 16 KB [buf][hd][key-chunk swizzled]
    __shared__ alignas(16) ushort Pl[4][16][40];    //  5 KB per-wave P scratch [q][key+pad]
    const int blk = blockIdx.x;
    const int h = blk & 7, qt = (blk >> 3) & 31, b = blk >> 8;
    const int t = threadIdx.x;
    const int w = t >> 6, lane = t & 63, quad = lane >> 4, li = lane & 15;
    const int q0 = qt * 64 + w * 16;
    const ushort* Qh = Qb + (size_t)(b * H_ + h) * L_ * HD_;
    const ushort* Kh = Kb + (size_t)(b * H_ + h) * L_ * HD_;
    const ushort* Vh = Vt + (size_t)(b * H_ + h) * HD_ * L_;
    const int* mb = mask + b * L_;

    // block-uniform unmasked-key count (recomputed from mask: no d_out dependency)
    int cm = 0;
    for (int c = lane; c < L_; c += 64) cm += mb[c];
    cm += __shfl_xor(cm, 32, 64);
    cm += __shfl_xor(cm, 16, 64);
    cm += __shfl_xor(cm, 8, 64);
    cm += __shfl_xor(cm, 4, 64);
    cm += __shfl_xor(cm, 2, 64);
    cm += __shfl_xor(cm, 1, 64);
    const int cnt = cm;
    int cnt_pad = (cnt + 31) & ~31;
    if (cnt_pad < 32) cnt_pad = 32;              // NaN guard (unreachable for real input)

    // DMA source pointers (lane-dependent; per-tile offset added at issue).
    // K slot (key,p) holds global hd-chunk p ^ (key&15); lane -> key=seg*4+(l>>4), p=l&15.
    // V slot (hd,p)  holds global key-chunk p ^ (hd&3);  lane -> hd=seg*16+(l>>2), p=l&3.
    const ushort* kgp[2]; const ushort* vgp[2];
    for (int i = 0; i < 2; i++) {
        int seg = w * 2 + i;                       // 0..7
        int key = seg * 4 + (lane >> 4);           // 0..31
        int ck  = (lane & 15) ^ (key & 15);
        kgp[i] = Kh + (size_t)key * HD_ + ck * 8;
        int hd  = seg * 16 + (lane >> 2);          // 0..127
        int cv  = (lane & 3) ^ (hd & 3);
        vgp[i] = Vh + (size_t)hd * L_ + cv * 8;
    }

    // prologue: DMA tile 0 into buf 0
    for (int i = 0; i < 2; i++) dma16(kgp[i], &Ks[0][0][0] + (w * 2 + i) * 512);
    for (int i = 0; i < 2; i++) dma16(vgp[i], &Vs[0][0][0] + (w * 2 + i) * 512);

    // Q as B-fragments (global, linear): qf[kf], n = q = li
    bf16x8 qf[4];
    for (int kf = 0; kf < 4; kf++)
        qf[kf] = *(const bf16x8*)&Qh[(size_t)(q0 + li) * HD_ + kf * 32 + quad * 8];

    float mrun = -1e30f, lrun = 0.f;
    f32x4 acc[8] = {};   // PV C-layout: row q = quad*4+r, col hd = li + 16*nf2

    int buf = 0;
    for (int n0 = 0; n0 < cnt_pad; n0 += 32, buf ^= 1) {
        __syncthreads();   // buf's DMA drained+visible; all waves past prior buf reads

        if (n0 + 32 < cnt_pad) {  // uniform: issue next tile's DMA into other buffer
            int nb = buf ^ 1;
            for (int i = 0; i < 2; i++)
                dma16(kgp[i] + (size_t)(n0 + 32) * HD_, &Ks[nb][0][0] + (w * 2 + i) * 512);
            for (int i = 0; i < 2; i++)
                dma16(vgp[i] + (n0 + 32), &Vs[nb][0][0] + (w * 2 + i) * 512);
        }

        // S^T = K(A) x Q^T(B): s[mt][r]: key = mt*16+quad*4+r, q = li
        f32x4 s[2] = {};
        for (int kf = 0; kf < 4; kf++) {
            bf16x8 kfr[2];
            for (int mt = 0; mt < 2; mt++)
                kfr[mt] = *(const bf16x8*)&Ks[buf][mt * 16 + li][((kf * 4 + quad) ^ li) * 8];
            for (int mt = 0; mt < 2; mt++)
                s[mt] = __builtin_amdgcn_mfma_f32_16x16x32_bf16(kfr[mt], qf[kf], s[mt], 0, 0, 0);
        }

        if (n0 + 32 > cnt) {  // tail tile only (uniform branch): clamp pad keys
            for (int mt = 0; mt < 2; mt++)
                for (int r = 0; r < 4; r++)
                    if (n0 + mt * 16 + quad * 4 + r >= cnt) s[mt][r] = -1e30f;
        }

        // softmax over this 32-key tile (q = li)
        float a0 = fmaxf(fmaxf(s[0][0], s[0][1]), fmaxf(s[0][2], s[0][3]));
        float a1 = fmaxf(fmaxf(s[1][0], s[1][1]), fmaxf(s[1][2], s[1][3]));
        float nm = fmaxf(a0, a1);
        nm = fmaxf(nm, __shfl_xor(nm, 16, 64));
        nm = fmaxf(nm, __shfl_xor(nm, 32, 64));
        float mnew = fmaxf(mrun, nm);
        float alpha = __expf(mrun - mnew);
        mrun = mnew;
        float rs = 0.f;
        for (int mt = 0; mt < 2; mt++)
            for (int r = 0; r < 4; r++) {
                float p = __expf(s[mt][r] - mnew);
                s[mt][r] = p;
                rs += p;
            }
        rs += __shfl_xor(rs, 16, 64);
        rs += __shfl_xor(rs, 32, 64);
        lrun = lrun * alpha + rs;

        // rescale acc only when the running max actually moved (common case: skip)
        if (__any(alpha != 1.0f)) {
            int sb = (lane & 48) | (quad * 4);     // lane with li = quad*4 (+r)
            float ar0 = __shfl(alpha, sb + 0, 64);
            float ar1 = __shfl(alpha, sb + 1, 64);
            float ar2 = __shfl(alpha, sb + 2, 64);
            float ar3 = __shfl(alpha, sb + 3, 64);
            for (int nf2 = 0; nf2 < 8; nf2++) {
                acc[nf2][0] *= ar0;
                acc[nf2][1] *= ar1;
                acc[nf2][2] *= ar2;
                acc[nf2][3] *= ar3;
            }
        }

        // P write: Pl[w][q=li][key = mt*16+quad*4+r]
        for (int mt = 0; mt < 2; mt++) {
            ushort4 pk = { f2bf(s[mt][0]), f2bf(s[mt][1]),
                           f2bf(s[mt][2]), f2bf(s[mt][3]) };
            *(ushort4*)&Pl[w][li][mt * 16 + quad * 4] = pk;
        }

        // PV: A = P (per-wave LDS, m=q=li, k=key), B = V from staged LDS
        bf16x8 pa = *(const bf16x8*)&Pl[w][li][quad * 8];
        for (int nf2 = 0; nf2 < 8; nf2++) {
            bf16x8 vb = *(const bf16x8*)&Vs[buf][nf2 * 16 + li][(quad ^ (li & 3)) * 8];
            acc[nf2] = __builtin_amdgcn_mfma_f32_16x16x32_bf16(pa, vb, acc[nf2], 0, 0, 0);
        }
    }

    // epilogue: redistribute 1/l to row-space, float4 stores (4 consecutive l)
    float inv = 1.0f / lrun;
    int sb = (lane & 48) | (quad * 4);
    float i0 = __shfl(inv, sb + 0, 64);
    float i1 = __shfl(inv, sb + 1, 64);
    float i2 = __shfl(inv, sb + 2, 64);
    float i3 = __shfl(inv, sb + 3, 64);
    int l = q0 + quad * 4;
    for (int nf2 = 0; nf2 < 8; nf2++) {
        int d = h * HD_ + nf2 * 16 + li;
        float4 o4 = { acc[nf2][0] * i0, acc[nf2][1] * i1,
                      acc[nf2][2] * i2, acc[nf2][3] * i3 };
        *(float4*)&out[((size_t)(b * D_ + d)) * L_ + l] = o4;
    }
}

extern "C" void kernel_launch(void* const* d_in, const int* in_sizes, int n_in,
                              void* d_out, int out_size, void* d_ws, size_t ws_size,
                              hipStream_t stream) {
    // Bind inputs by element count (all distinct).
    const float* query = nullptr;  // 4*1024*2048 = 8388608
    const int*   mask  = nullptr;  // 4*2048     = 8192
    const float* W1    = nullptr;  // 2048*1024  = 2097152
    const float* Wq    = nullptr;  // 1024*1024  = 1048576
    for (int i = 0; i < n_in; i++) {
        switch (in_sizes[i]) {
            case 8388608: query = (const float*)d_in[i]; break;
            case 8192:    mask  = (const int*)d_in[i];   break;
            case 2097152: W1    = (const float*)d_in[i]; break;
            case 1048576: Wq    = (const float*)d_in[i]; break;
        }
    }
    float* out = (float*)d_out;  // [4,1024,2048] fp32 (reference output dtype)

    if (ws_size < 50331648u || !query || !mask || !W1 || !Wq) {
        hipLaunchKernelGGL(k_zero_out, dim3((out_size + 255) / 256), dim3(256), 0, stream,
                           out, out_size);
        return;
    }

    // d_out (32 MB fp32) is dead until k_attn -> use its head as projection scratch.
    // cidx/cnt also live here: written by k_scan, read ONLY by k_proj (pre-attn).
    ushort* Wb = (ushort*)d_out;                       // [3072][1024]      6291456 B
    ushort* Xt = (ushort*)((char*)d_out + 6291456);    // [4][2048][1024]  16777216 B
    int* cidx  = (int*)((char*)d_out + 23068672);      // [4][2048]           32768 B
    int* cnt   = (int*)((char*)d_out + 23101440);      // [4]                    16 B
    char* ws = (char*)d_ws;                            // Qb|Kb|Vt = 48 MB <= gate
    ushort* Qb = (ushort*)(ws + 0);
    ushort* Kb = (ushort*)(ws + 16777216);
    ushort* Vt = (ushort*)(ws + 33554432);

    hipLaunchKernelGGL(k_convert_w, dim3(3072), dim3(256), 0, stream, W1, Wq, Wb);
    hipLaunchKernelGGL(k_transpose, dim3(64, 32, 4), dim3(32, 8), 0, stream, query, Xt);
    hipLaunchKernelGGL(k_scan, dim3(4), dim3(64), 0, stream, mask, cidx, cnt);
    hipLaunchKernelGGL(k_proj, dim3(16, 24, 4), dim3(256), 0, stream, Wb, Xt, cidx, cnt, Qb, Kb, Vt);
    hipLaunchKernelGGL(k_attn, dim3(1024), dim3(256), 0, stream, Qb, Kb, Vt, mask, out);
}